// Round 6
// baseline (1153.682 us; speedup 1.0000x reference)
//
#include <hip/hip_runtime.h>
#include <hip/hip_bf16.h>

typedef float f32x4 __attribute__((ext_vector_type(4)));
typedef float f32x2 __attribute__((ext_vector_type(2)));
typedef int   i32x4 __attribute__((ext_vector_type(4)));
typedef int   i32x8 __attribute__((ext_vector_type(8)));

#define LOG_SQRT_2PI 0.91893853320467274f

static constexpr int BSZ  = 16384;
static constexpr int OBSN = 376;
static constexpr int HD   = 512;
static constexpr int NACT = 17;

__device__ __forceinline__ unsigned char f2fp8(float v) {
  return (unsigned char)(__builtin_amdgcn_cvt_pk_fp8_f32(v, v, 0, false) & 0xFF);
}

__device__ __forceinline__ void gl16(const unsigned char* g, unsigned char* l) {
  __builtin_amdgcn_global_load_lds((const __attribute__((address_space(1))) void*)g,
                                   (__attribute__((address_space(3))) void*)l, 16, 0, 0);
}

// XCD-aware tile remap: blocks sharing an A-slab (same by,bz; all bx) get consecutive
// slots on the SAME XCD (id%8 round-robin). Requires grid % 8 == 0.
__device__ __forceinline__ void xcd_map(int id, int gx, int gy, int& bx, int& by, int& bz) {
  int p = id & 7, l = id >> 3;
  bx = l % gx;
  int g = (l / gx) * 8 + p;
  by = g % gy;
  bz = g / gy;
}

// ---------------- prep kernels ----------------

// x [B,376] f32 -> [B,512] fp8 (zero pad)
__global__ void k_cvt_pad8(const float* __restrict__ src, unsigned char* __restrict__ dst) {
  long i = (long)blockIdx.x * 256 + threadIdx.x;
  if (i >= (long)BSZ * HD) return;
  long r = i >> 9;
  int  c = (int)(i & 511);
  dst[i] = f2fp8(c < OBSN ? src[r * OBSN + c] : 0.f);
}

// dst[n][k] = fp8(scale * src[k][n]); zero for k >= K. batched via blockIdx.z.
__global__ void k_packT8(const float* __restrict__ src, unsigned char* __restrict__ dst,
                         int K, int N, int Kpad, long sstride, long dstride, float scale) {
  __shared__ float t[32][33];
  src += (long)blockIdx.z * sstride;
  dst += (long)blockIdx.z * dstride;
  int k0 = blockIdx.y * 32, n0 = blockIdx.x * 32;
#pragma unroll
  for (int ii = 0; ii < 4; ++ii) {
    int i = ii * 8 + threadIdx.y;
    int k = k0 + i, n = n0 + threadIdx.x;
    t[i][threadIdx.x] = (k < K && n < N) ? src[(long)k * N + n] : 0.f;
  }
  __syncthreads();
#pragma unroll
  for (int ii = 0; ii < 4; ++ii) {
    int i = ii * 8 + threadIdx.y;
    int n = n0 + i, k = k0 + threadIdx.x;
    if (n < N && k < Kpad) dst[(long)n * Kpad + k] = f2fp8(scale * t[threadIdx.x][i]);
  }
}

// merged base-net weights [layer][z=net*8+m][n][k]: net 0 = critic, 1 = actor.
__global__ void k_packw8(const float* __restrict__ aW, const float* __restrict__ cW,
                         unsigned char* __restrict__ dst) {
  __shared__ float t[32][33];
  const int z = blockIdx.z;                       // 0..47
  const int layer = z >> 4, zz = z & 15, net = zz >> 3, m = zz & 7;
  const float* src = (net ? aW : cW) + (long)(layer * 8 + m) * 262144;
  unsigned char* d = dst + (long)z * 262144;
  int k0 = blockIdx.y * 32, n0 = blockIdx.x * 32;
#pragma unroll
  for (int ii = 0; ii < 4; ++ii) {
    int i = ii * 8 + threadIdx.y;
    t[i][threadIdx.x] = src[(long)(k0 + i) * 512 + n0 + threadIdx.x];
  }
  __syncthreads();
#pragma unroll
  for (int ii = 0; ii < 4; ++ii) {
    int i = ii * 8 + threadIdx.y;
    d[(long)(n0 + i) * 512 + k0 + threadIdx.x] = f2fp8(16.f * t[threadIdx.x][i]);
  }
}

// merged biases lb[layer][z=net*8+m][n]
__global__ void k_pack_lb(const float* __restrict__ a_b, const float* __restrict__ c_b,
                          float* __restrict__ lb) {
  int i = blockIdx.x * 256 + threadIdx.x;         // 3*16*512 = 24576
  if (i >= 24576) return;
  int layer = i >> 13, zz = (i >> 9) & 15, n = i & 511;
  int net = zz >> 3, m = zz & 7;
  lb[i] = (net ? a_b : c_b)[(layer * 8 + m) * 512 + n];
}

// final-head weights -> fp8, x64 scaled, transposed [32 pad][4096]
__global__ void k_packwf8(const float* __restrict__ aWf, const float* __restrict__ cWf,
                          unsigned char* __restrict__ dsta, unsigned char* __restrict__ dstc) {
  int i = blockIdx.x * 256 + threadIdx.x;   // 131072 total
  int n = i >> 12, k = i & 4095;
  dsta[i] = (n < NACT) ? f2fp8(64.f * aWf[(long)k * NACT + n]) : (unsigned char)0;
  dstc[i] = (n < 1)    ? f2fp8(64.f * cWf[k])                  : (unsigned char)0;
}

__global__ void k_pack_rb(const float* __restrict__ a_rb, const float* __restrict__ c_rb,
                          float* __restrict__ rb) {
  int i = threadIdx.x;  // 384 threads
  rb[i] = (i < 192) ? a_rb[i] : c_rb[i - 192];
}

__global__ void k_sum_bf(const float* __restrict__ a_bf, const float* __restrict__ c_bf,
                         float* __restrict__ sa, float* __restrict__ sc) {
  int a = threadIdx.x;
  if (a < NACT) { float s = 0.f; for (int m = 0; m < 8; ++m) s += a_bf[m * NACT + a]; sa[a] = s; }
  if (a == 0)   { float s = 0.f; for (int m = 0; m < 8; ++m) s += c_bf[m];            sc[0] = s; }
}

// ---------------- unified MX fp8 GEMM (LDS path): encoder / routing ----------------
// OP: 1 = tanh -> fp8 (encoder-1); 5 = tanh->fp8 AND fp8(relu(tanh*temb)) (encoder-2)
//     4 = softmax over col-octets -> f32 (routing)
template <int OP>
__global__ __launch_bounds__(256, 4)
void k_gemm8(const unsigned char* __restrict__ A, const unsigned char* __restrict__ Bt,
             void* __restrict__ Cv, const float* __restrict__ bias,
             int N, int K, int lda, int ldc, int gx, int gy,
             const int* __restrict__ tidx, const float* __restrict__ temb,
             unsigned char* __restrict__ out2) {
  __shared__ alignas(16) unsigned char sA[128 * 128];
  __shared__ alignas(16) unsigned char sB[128 * 128];
  int bx, by, z;
  xcd_map(blockIdx.x, gx, gy, bx, by, z);
  const int tid  = threadIdx.x;
  const int wave = tid >> 6, lane = tid & 63;
  const int wr = (wave >> 1) * 64, wc = (wave & 1) * 64;
  const int row0 = by * 128, col0 = bx * 128;
  const int lcol = lane & 15, quad = lane >> 4;
  const int sw7 = lcol & 7;
  const int c0 = ((2 * quad)     ^ sw7) * 16;
  const int c1 = ((2 * quad + 1) ^ sw7) * 16;
  const int raA0 = (wr + lcol) * 128 + c0, raA1 = (wr + lcol) * 128 + c1;
  const int rbB0 = (wc + lcol) * 128 + c0, rbB1 = (wc + lcol) * 128 + c1;
  int aOff[4], bOff[4];
#pragma unroll
  for (int i = 0; i < 4; ++i) {
    int u = i * 256 + tid;
    int r = u >> 3, gc = (u & 7) ^ (r & 7);
    aOff[i] = (row0 + r) * lda + gc * 16;
    bOff[i] = (col0 + r) * K + gc * 16;
  }

  f32x4 acc[4][4] = {};

  for (int kt = 0; kt < K; kt += 128) {
#pragma unroll
    for (int i = 0; i < 4; ++i) gl16(A + aOff[i] + kt, &sA[i * 4096 + tid * 16]);
#pragma unroll
    for (int i = 0; i < 4; ++i) gl16(Bt + bOff[i] + kt, &sB[i * 4096 + tid * 16]);
    __syncthreads();
    i32x8 bv[4];
#pragma unroll
    for (int ni = 0; ni < 4; ++ni) {
      i32x4 blo = *(const i32x4*)&sB[rbB0 + ni * 2048];
      i32x4 bhi = *(const i32x4*)&sB[rbB1 + ni * 2048];
      bv[ni] = (i32x8){blo[0], blo[1], blo[2], blo[3], bhi[0], bhi[1], bhi[2], bhi[3]};
    }
#pragma unroll
    for (int mi = 0; mi < 4; ++mi) {
      i32x4 alo = *(const i32x4*)&sA[raA0 + mi * 2048];
      i32x4 ahi = *(const i32x4*)&sA[raA1 + mi * 2048];
      i32x8 af = (i32x8){alo[0], alo[1], alo[2], alo[3], ahi[0], ahi[1], ahi[2], ahi[3]};
#pragma unroll
      for (int ni = 0; ni < 4; ++ni)
        acc[mi][ni] = __builtin_amdgcn_mfma_scale_f32_16x16x128_f8f6f4(
            bv[ni], af, acc[mi][ni], 0, 0, 0, 0x7F, 0, 0x7F);
    }
    __syncthreads();
  }

#pragma unroll
  for (int ni = 0; ni < 4; ++ni) {
    int colb = col0 + wc + ni * 16 + quad * 4;
    if (colb >= N) continue;
    float4 bw = *(const float4*)&bias[colb];
#pragma unroll
    for (int mi = 0; mi < 4; ++mi) {
      int rowg = row0 + wr + mi * 16 + lcol;
      float v0 = acc[mi][ni][0] * 0.0625f + bw.x;
      float v1 = acc[mi][ni][1] * 0.0625f + bw.y;
      float v2 = acc[mi][ni][2] * 0.0625f + bw.z;
      float v3 = acc[mi][ni][3] * 0.0625f + bw.w;
      long idx = (long)rowg * ldc + colb;
      if (OP == 1) {
        float t0 = tanhf(v0), t1 = tanhf(v1), t2 = tanhf(v2), t3 = tanhf(v3);
        unsigned d = __builtin_amdgcn_cvt_pk_fp8_f32(t0, t1, 0, false);
        d = __builtin_amdgcn_cvt_pk_fp8_f32(t2, t3, d, true);
        *(unsigned*)&((unsigned char*)Cv)[idx] = d;
      } else if (OP == 5) {
        float t0 = tanhf(v0), t1 = tanhf(v1), t2 = tanhf(v2), t3 = tanhf(v3);
        unsigned d = __builtin_amdgcn_cvt_pk_fp8_f32(t0, t1, 0, false);
        d = __builtin_amdgcn_cvt_pk_fp8_f32(t2, t3, d, true);
        *(unsigned*)&((unsigned char*)Cv)[idx] = d;
        int tk = tidx[rowg];
        float4 te = *(const float4*)&temb[(long)tk * HD + colb];
        unsigned e = __builtin_amdgcn_cvt_pk_fp8_f32(fmaxf(t0 * te.x, 0.f), fmaxf(t1 * te.y, 0.f), 0, false);
        e = __builtin_amdgcn_cvt_pk_fp8_f32(fmaxf(t2 * te.z, 0.f), fmaxf(t3 * te.w, 0.f), e, true);
        *(unsigned*)&out2[idx] = e;
      } else if (OP == 4) {
        float mx = fmaxf(fmaxf(v0, v1), fmaxf(v2, v3));
        mx = fmaxf(mx, __shfl_xor(mx, 16));
        float e0 = __expf(v0 - mx), e1 = __expf(v1 - mx), e2 = __expf(v2 - mx), e3 = __expf(v3 - mx);
        float s = e0 + e1 + e2 + e3;
        s += __shfl_xor(s, 16);
        float inv = 1.f / s;
        *(float4*)&((float*)Cv)[idx] = make_float4(e0 * inv, e1 * inv, e2 * inv, e3 * inv);
      }
    }
  }
}

// ---------------- FUSED base-net layer: GEMM (8 modules) + routed combine ----------------
// Block: 64 rows x 128 h-cols x one net; 8 waves, wave w = module.
// A staged in LDS per K-tile (64 KB, coalesced gload_lds, XOR-chunk swizzle);
// B fragments direct from global (weights 2 MB/net/layer -> L2-resident);
// outs = relu(acc/16+b) packed fp8 into sO (swizzled); then g[b][i][h] = sum_j P*outs
// computed from LDS and written coalesced. Eliminates the separate combine kernel.
// AMODE 0: A = fs8 [B,512] shared across modules (layer 1).
// AMODE 1: A = g_prev [B,8192], module slice at net*4096 + j*512 (layers 2,3).
template <int AMODE>
__global__ __launch_bounds__(512, 2)
void k_gemmF(const unsigned char* __restrict__ A, const unsigned char* __restrict__ W,
             const float* __restrict__ lb, const float* __restrict__ probs,
             unsigned char* __restrict__ g, int gy, int poffC, int poffA) {
  __shared__ alignas(16) unsigned char sA[65536];
  __shared__ alignas(16) unsigned char sO[65536];
  int hb, slab, net;
  xcd_map(blockIdx.x, 4, gy, hb, slab, net);
  const int tid = threadIdx.x;
  const int w = tid >> 6, lane = tid & 63;
  const int lcol = lane & 15, quad = lane >> 4;
  const int row0 = slab * 64;
  const int h0 = hb * 128;
  const int sw7 = lcol & 7;
  const int c0 = ((2 * quad)     ^ sw7) * 16;
  const int c1 = ((2 * quad + 1) ^ sw7) * 16;
  // this wave's weight fragment base: W[z = net*8+w][n = h0+lcol..][k]
  const unsigned char* Wz = W + (long)(net * 8 + w) * 262144 + (h0 + lcol) * 512 + quad * 32;

  f32x4 acc[4][8] = {};

  if (AMODE == 0) {
    // stage ALL of A (64 rows x 512 k = 32 KB) once; layout [t][64][128] swizzled
#pragma unroll
    for (int i = 0; i < 4; ++i) {
      int u = i * 512 + tid;
      int r = (u >> 3) & 63, ch = (u & 7) ^ (r & 7);
      gl16(A + (row0 + r) * 512 + (u >> 9) * 128 + ch * 16, &sA[u * 16]);
    }
    __syncthreads();
#pragma unroll
    for (int t = 0; t < 4; ++t) {
      const int kt = t * 128;
      const unsigned char* sAb = sA + t * 8192;
      i32x8 bv[8];
#pragma unroll
      for (int ni = 0; ni < 8; ++ni) {
        i32x4 lo = *(const i32x4*)(Wz + ni * 8192 + kt);
        i32x4 hi = *(const i32x4*)(Wz + ni * 8192 + kt + 16);
        bv[ni] = (i32x8){lo[0], lo[1], lo[2], lo[3], hi[0], hi[1], hi[2], hi[3]};
      }
#pragma unroll
      for (int mi = 0; mi < 4; ++mi) {
        int ra = (mi * 16 + lcol) * 128;
        i32x4 lo = *(const i32x4*)&sAb[ra + c0];
        i32x4 hi = *(const i32x4*)&sAb[ra + c1];
        i32x8 af = (i32x8){lo[0], lo[1], lo[2], lo[3], hi[0], hi[1], hi[2], hi[3]};
#pragma unroll
        for (int ni = 0; ni < 8; ++ni)
          acc[mi][ni] = __builtin_amdgcn_mfma_scale_f32_16x16x128_f8f6f4(
              bv[ni], af, acc[mi][ni], 0, 0, 0, 0x7F, 0, 0x7F);
      }
    }
    __syncthreads();
  } else {
#pragma unroll 1
    for (int t = 0; t < 4; ++t) {
      const int kt = t * 128;
      // stage: all 8 modules' 64x128 slices (64 KB): u -> j = u>>9, r, chunk
#pragma unroll
      for (int i = 0; i < 8; ++i) {
        int u = i * 512 + tid;
        int j = u >> 9, rem = u & 511;
        int r = rem >> 3, ch = (rem & 7) ^ (r & 7);
        gl16(A + (long)(row0 + r) * 8192 + net * 4096 + j * 512 + kt + ch * 16, &sA[u * 16]);
      }
      __syncthreads();
      const unsigned char* sAb = sA + (w << 13);
      i32x8 bv[8];
#pragma unroll
      for (int ni = 0; ni < 8; ++ni) {
        i32x4 lo = *(const i32x4*)(Wz + ni * 8192 + kt);
        i32x4 hi = *(const i32x4*)(Wz + ni * 8192 + kt + 16);
        bv[ni] = (i32x8){lo[0], lo[1], lo[2], lo[3], hi[0], hi[1], hi[2], hi[3]};
      }
#pragma unroll
      for (int mi = 0; mi < 4; ++mi) {
        int ra = (mi * 16 + lcol) * 128;
        i32x4 lo = *(const i32x4*)&sAb[ra + c0];
        i32x4 hi = *(const i32x4*)&sAb[ra + c1];
        i32x8 af = (i32x8){lo[0], lo[1], lo[2], lo[3], hi[0], hi[1], hi[2], hi[3]};
#pragma unroll
        for (int ni = 0; ni < 8; ++ni)
          acc[mi][ni] = __builtin_amdgcn_mfma_scale_f32_16x16x128_f8f6f4(
              bv[ni], af, acc[mi][ni], 0, 0, 0, 0x7F, 0, 0x7F);
      }
      __syncthreads();
    }
  }

  // ---- epilogue A: relu -> fp8 -> sO[j][64r][128h] (chunk XOR swizzle) ----
#pragma unroll
  for (int ni = 0; ni < 8; ++ni) {
    int col = ni * 16 + quad * 4;
    float4 bw = *(const float4*)&lb[(net * 8 + w) * 512 + h0 + col];
#pragma unroll
    for (int mi = 0; mi < 4; ++mi) {
      int row = mi * 16 + lcol;
      float v0 = fmaxf(acc[mi][ni][0] * 0.0625f + bw.x, 0.f);
      float v1 = fmaxf(acc[mi][ni][1] * 0.0625f + bw.y, 0.f);
      float v2 = fmaxf(acc[mi][ni][2] * 0.0625f + bw.z, 0.f);
      float v3 = fmaxf(acc[mi][ni][3] * 0.0625f + bw.w, 0.f);
      unsigned d = __builtin_amdgcn_cvt_pk_fp8_f32(v0, v1, 0, false);
      d = __builtin_amdgcn_cvt_pk_fp8_f32(v2, v3, d, true);
      *(unsigned*)&sO[(w << 13) + row * 128 + ((ni ^ (row & 7)) << 4) + quad * 4] = d;
    }
  }
  __syncthreads();

  // ---- epilogue B: combine. wave w = output module i. lane = (rb, hp). ----
  const int rb = lane >> 3, hp = lane & 7;
  const int poff = net ? poffA : poffC;
#pragma unroll
  for (int k = 0; k < 8; ++k) {
    const int r = rb + k * 8;
    const float* pr = &probs[(long)(row0 + r) * 384 + poff + w * 8];
    float4 pA = *(const float4*)pr;
    float4 pB = *(const float4*)(pr + 4);
    float p8[8] = {pA.x, pA.y, pA.z, pA.w, pB.x, pB.y, pB.z, pB.w};
    float ga[16] = {};
#pragma unroll
    for (int j = 0; j < 8; ++j) {
      i32x4 o4 = *(const i32x4*)&sO[(j << 13) + r * 128 + ((hp ^ rb) << 4)];
      float pw = p8[j];
#pragma unroll
      for (int dw = 0; dw < 4; ++dw) {
        f32x2 lo = __builtin_amdgcn_cvt_pk_f32_fp8((unsigned)o4[dw], false);
        f32x2 hi = __builtin_amdgcn_cvt_pk_f32_fp8((unsigned)o4[dw], true);
        ga[dw * 4 + 0] += pw * lo.x;
        ga[dw * 4 + 1] += pw * lo.y;
        ga[dw * 4 + 2] += pw * hi.x;
        ga[dw * 4 + 3] += pw * hi.y;
      }
    }
    i32x4 gg;
#pragma unroll
    for (int dw = 0; dw < 4; ++dw) {
      unsigned d = __builtin_amdgcn_cvt_pk_fp8_f32(ga[dw * 4 + 0], ga[dw * 4 + 1], 0, false);
      d = __builtin_amdgcn_cvt_pk_fp8_f32(ga[dw * 4 + 2], ga[dw * 4 + 3], d, true);
      gg[dw] = (int)d;
    }
    *(i32x4*)&g[(long)(row0 + r) * 8192 + net * 4096 + w * 512 + h0 + hp * 16] = gg;
  }
}

// ---------------- MFMA head: out[:, ooff..) = g8[rows,4096(of lda)] * (64*Wf)^T / 64 + bsum ----
template <int NOUT>
__global__ __launch_bounds__(256)
void k_head8(const unsigned char* __restrict__ A, const unsigned char* __restrict__ Bt,
             const float* __restrict__ bsum, float* __restrict__ out, int lda, int ooff) {
  __shared__ alignas(16) unsigned char sA[64 * 64];
  __shared__ alignas(16) unsigned char sB[32 * 64];
  const int tid = threadIdx.x;
  const int wave = tid >> 6, lane = tid & 63;
  const int row0 = blockIdx.x * 64;
  const int lcol = lane & 15, quad = lane >> 4;
  const int sw = (lcol >> 1) & 3;
  const int co0 = (((quad >> 1)    ) ^ sw) * 16 + (quad & 1) * 8;
  const int co1 = (((quad >> 1) + 2) ^ sw) * 16 + (quad & 1) * 8;
  f32x4 acc[2] = {};

  for (int kt = 0; kt < 4096; kt += 64) {
    {
      int r = tid >> 2, gc = (tid & 3) ^ ((tid >> 3) & 3);
      gl16(A + (long)(row0 + r) * lda + kt + gc * 16, &sA[tid * 16]);
    }
    if (tid < 128) {
      int r = tid >> 2, gc = (tid & 3) ^ ((tid >> 3) & 3);
      gl16(Bt + (long)r * 4096 + kt + gc * 16, &sB[tid * 16]);
    }
    __syncthreads();
    long af[2], bv[2][2];
    int ra = (wave * 16 + lcol) * 64;
    af[0] = *(const long*)&sA[ra + co0];
    af[1] = *(const long*)&sA[ra + co1];
#pragma unroll
    for (int ni = 0; ni < 2; ++ni) {
      int rbq = (ni * 16 + lcol) * 64;
      bv[0][ni] = *(const long*)&sB[rbq + co0];
      bv[1][ni] = *(const long*)&sB[rbq + co1];
    }
#pragma unroll
    for (int kk = 0; kk < 2; ++kk)
#pragma unroll
      for (int ni = 0; ni < 2; ++ni)
        acc[ni] = __builtin_amdgcn_mfma_f32_16x16x32_fp8_fp8(af[kk], bv[kk][ni], acc[ni], 0, 0, 0);
    __syncthreads();
  }

#pragma unroll
  for (int ni = 0; ni < 2; ++ni) {
    int col = ni * 16 + lcol;
    if (col >= NOUT) continue;
#pragma unroll
    for (int r = 0; r < 4; ++r) {
      int row = row0 + wave * 16 + quad * 4 + r;
      out[(long)row * 20 + ooff + col] = acc[ni][r] * 0.015625f + bsum[col];
    }
  }
}

__global__ void k_logstd(const float* __restrict__ ls, float* __restrict__ out) {
  float lp = 0.f, ent = 0.f;
#pragma unroll
  for (int a = 0; a < NACT; ++a) {
    float v = ls[a];
    lp  += -v - LOG_SQRT_2PI;
    ent += 0.5f + LOG_SQRT_2PI + v;
  }
  long b = (long)blockIdx.x * 256 + threadIdx.x;
  if (b < BSZ) { out[b * 20 + 17] = lp; out[b * 20 + 18] = ent; }
}

// ---------------- host ----------------

extern "C" void kernel_launch(void* const* d_in, const int* in_sizes, int n_in,
                              void* d_out, int out_size, void* d_ws, size_t ws_size,
                              hipStream_t stream) {
  const float* x        = (const float*)d_in[0];
  const int*   task_idx = (const int*)d_in[1];
  const float* enc_W1   = (const float*)d_in[2];
  const float* enc_b1   = (const float*)d_in[3];
  const float* enc_W2   = (const float*)d_in[4];
  const float* enc_b2   = (const float*)d_in[5];
  const float* task_emb = (const float*)d_in[6];
  const float* a_rW     = (const float*)d_in[7];
  const float* a_rb     = (const float*)d_in[8];
  const float* c_rW     = (const float*)d_in[9];
  const float* c_rb     = (const float*)d_in[10];
  const float* a_W      = (const float*)d_in[11];
  const float* a_b      = (const float*)d_in[12];
  const float* a_Wf     = (const float*)d_in[13];
  const float* a_bf     = (const float*)d_in[14];
  const float* c_W      = (const float*)d_in[15];
  const float* c_b      = (const float*)d_in[16];
  const float* c_Wf     = (const float*)d_in[17];
  const float* c_bf     = (const float*)d_in[18];
  const float* logstd   = (const float*)d_in[19];
  float* out = (float*)d_out;

  char* ws = (char*)d_ws;
  size_t off = 0;
  auto carve = [&](size_t bytes) {
    char* p = ws + off;
    off += (bytes + 255) & ~(size_t)255;
    return p;
  };
  // ---- fixed region ----
  unsigned char* W8 = (unsigned char*)carve((size_t)48 * 262144);   // merged fp8 weights x16
  unsigned char* W1T8 = (unsigned char*)carve((size_t)512 * 512);   // enc W1^T fp8 x16, K-pad 512
  unsigned char* W2T8 = (unsigned char*)carve((size_t)512 * 512);   // enc W2^T fp8 x16
  unsigned char* rWT8 = (unsigned char*)carve((size_t)384 * 512);   // routing W^T fp8 x16
  float* rball = (float*)carve(384 * 4);
  float* lb    = (float*)carve(3 * 16 * 512 * 4);                   // merged biases
  unsigned char* WfaT8 = (unsigned char*)carve((size_t)32 * 4096);  // head weights fp8 x64, padded
  unsigned char* WfcT8 = (unsigned char*)carve((size_t)32 * 4096);
  float* bfa   = (float*)carve(128 * 4);
  float* bfc   = (float*)carve(128 * 4);
  unsigned char* fs8 = (unsigned char*)carve((size_t)BSZ * HD);
  float* lgt   = (float*)carve((size_t)BSZ * 384 * 4);

  // ---- fp8 ping-pong region ([Bc, 8192] each: critic cols 0..4096, actor 4096..8192) ----
  size_t remain = (ws_size > off) ? (ws_size - off) : 0;
  int Bc = 2048;
  for (int cand = BSZ; cand > 2048; cand >>= 1)
    if ((size_t)2 * cand * 8192 <= remain) { Bc = cand; break; }
  size_t half = (size_t)Bc * 8192;
  unsigned char* bufA8 = (unsigned char*)carve(half);
  unsigned char* bufB8 = (unsigned char*)carve(half);
  unsigned char* x8   = bufA8;   // [B,512] fp8, dead after enc1
  unsigned char* h18  = bufB8;   // [B,512] fp8, dead after enc2
  unsigned char* rel8 = bufA8;   // [B,512] fp8, dead after routing

  dim3 tb(32, 8);

  // ---- prep (all fp8 packs) ----
  k_cvt_pad8<<<(int)(((long)BSZ * HD + 255) / 256), 256, 0, stream>>>(x, x8);
  k_packT8<<<dim3(16, 16, 1), tb, 0, stream>>>(enc_W1, W1T8, OBSN, 512, 512, 0, 0, 16.f);
  k_packT8<<<dim3(16, 16, 1), tb, 0, stream>>>(enc_W2, W2T8, 512, 512, 512, 0, 0, 16.f);
  k_packT8<<<dim3(2, 16, 3),  tb, 0, stream>>>(a_rW, rWT8,             512, 64, 512, 512 * 64, 64 * 512, 16.f);
  k_packT8<<<dim3(2, 16, 3),  tb, 0, stream>>>(c_rW, rWT8 + 192 * 512, 512, 64, 512, 512 * 64, 64 * 512, 16.f);
  k_packw8<<<dim3(16, 16, 48), tb, 0, stream>>>(a_W, c_W, W8);
  k_pack_lb<<<96, 256, 0, stream>>>(a_b, c_b, lb);
  k_packwf8<<<512, 256, 0, stream>>>(a_Wf, c_Wf, WfaT8, WfcT8);
  k_pack_rb<<<1, 384, 0, stream>>>(a_rb, c_rb, rball);
  k_sum_bf<<<1, 32, 0, stream>>>(a_bf, c_bf, bfa, bfc);

  const int GY = BSZ / 128;
  // ---- encoder + routing (fp8 MX, LDS kernel) ----
  k_gemm8<1><<<4 * GY, 256, 0, stream>>>(x8, W1T8, h18, enc_b1, 512, 512, 512, 512,
                                         4, GY, nullptr, nullptr, nullptr);
  k_gemm8<5><<<4 * GY, 256, 0, stream>>>(h18, W2T8, fs8, enc_b2, 512, 512, 512, 512,
                                         4, GY, task_idx, task_emb, rel8);
  k_gemm8<4><<<3 * GY, 256, 0, stream>>>(rel8, rWT8, lgt, rball, 384, 512, 512, 384,
                                         3, GY, nullptr, nullptr, nullptr);

  // ---- base nets: fused GEMM+combine, 3 layers, chunked (Bc normally 16384) ----
  const size_t wlz = (size_t)16 * 262144;   // per-layer merged weight block
  for (int c0 = 0; c0 < BSZ; c0 += Bc) {
    const unsigned char* fs_c = fs8 + (long)c0 * 512;
    const float* pr_c  = lgt + (long)c0 * 384;
    float*       out_c = out + (long)c0 * 20;
    const int gyF = Bc / 64;

    k_gemmF<0><<<8 * gyF, 512, 0, stream>>>(fs_c, W8, lb, pr_c, bufA8, gyF, 192, 0);
    k_gemmF<1><<<8 * gyF, 512, 0, stream>>>(bufA8, W8 + wlz, lb + 8192, pr_c, bufB8,
                                            gyF, 192 + 64, 64);
    k_gemmF<1><<<8 * gyF, 512, 0, stream>>>(bufB8, W8 + 2 * wlz, lb + 16384, pr_c, bufA8,
                                            gyF, 192 + 128, 128);
    k_head8<1><<<Bc / 64, 256, 0, stream>>>(bufA8, WfcT8, bfc, out_c, 8192, 19);
    k_head8<NACT><<<Bc / 64, 256, 0, stream>>>(bufA8 + 4096, WfaT8, bfa, out_c, 8192, 0);
  }

  // ---- constants ----
  k_logstd<<<BSZ / 256, 256, 0, stream>>>(logstd, out);
}

// Round 7
// 757.543 us; speedup vs baseline: 1.5229x; 1.5229x over previous
//
#include <hip/hip_runtime.h>
#include <hip/hip_bf16.h>

typedef float f32x4 __attribute__((ext_vector_type(4)));
typedef float f32x2 __attribute__((ext_vector_type(2)));
typedef int   i32x4 __attribute__((ext_vector_type(4)));
typedef int   i32x8 __attribute__((ext_vector_type(8)));

#define LOG_SQRT_2PI 0.91893853320467274f

static constexpr int BSZ  = 16384;
static constexpr int OBSN = 376;
static constexpr int HD   = 512;
static constexpr int NACT = 17;

__device__ __forceinline__ unsigned char f2fp8(float v) {
  return (unsigned char)(__builtin_amdgcn_cvt_pk_fp8_f32(v, v, 0, false) & 0xFF);
}

__device__ __forceinline__ void gl16(const unsigned char* g, unsigned char* l) {
  __builtin_amdgcn_global_load_lds((const __attribute__((address_space(1))) void*)g,
                                   (__attribute__((address_space(3))) void*)l, 16, 0, 0);
}

// XCD-aware tile remap: blocks sharing an A-slab (same by,bz; all bx) get consecutive
// slots on the SAME XCD (id%8 round-robin). Requires grid % 8 == 0.
__device__ __forceinline__ void xcd_map(int id, int gx, int gy, int& bx, int& by, int& bz) {
  int p = id & 7, l = id >> 3;
  bx = l % gx;
  int g = (l / gx) * 8 + p;
  by = g % gy;
  bz = g / gy;
}

// ---------------- prep kernels ----------------

// x [B,376] f32 -> [B,512] fp8 (zero pad)
__global__ void k_cvt_pad8(const float* __restrict__ src, unsigned char* __restrict__ dst) {
  long i = (long)blockIdx.x * 256 + threadIdx.x;
  if (i >= (long)BSZ * HD) return;
  long r = i >> 9;
  int  c = (int)(i & 511);
  dst[i] = f2fp8(c < OBSN ? src[r * OBSN + c] : 0.f);
}

// dst[n][k] = fp8(scale * src[k][n]); zero for k >= K. batched via blockIdx.z.
__global__ void k_packT8(const float* __restrict__ src, unsigned char* __restrict__ dst,
                         int K, int N, int Kpad, long sstride, long dstride, float scale) {
  __shared__ float t[32][33];
  src += (long)blockIdx.z * sstride;
  dst += (long)blockIdx.z * dstride;
  int k0 = blockIdx.y * 32, n0 = blockIdx.x * 32;
#pragma unroll
  for (int ii = 0; ii < 4; ++ii) {
    int i = ii * 8 + threadIdx.y;
    int k = k0 + i, n = n0 + threadIdx.x;
    t[i][threadIdx.x] = (k < K && n < N) ? src[(long)k * N + n] : 0.f;
  }
  __syncthreads();
#pragma unroll
  for (int ii = 0; ii < 4; ++ii) {
    int i = ii * 8 + threadIdx.y;
    int n = n0 + i, k = k0 + threadIdx.x;
    if (n < N && k < Kpad) dst[(long)n * Kpad + k] = f2fp8(scale * t[threadIdx.x][i]);
  }
}

// base-net weights -> FRAGMENT-PACKED fp8 x16:
// Wp offset(z, t=k>>7, nb=n>>4, lane=((k>>5)&3)*16 + (n&15)) * 32 + (k&31)
// so a wave's bv load is base + lane*32 (+16): fully coalesced dwordx4.
// z = layer*16 + net*8 + m; net 0 = critic, 1 = actor.
__global__ void k_packwF(const float* __restrict__ aW, const float* __restrict__ cW,
                         unsigned char* __restrict__ dst) {
  long i = (long)blockIdx.x * 256 + threadIdx.x;   // 48*262144
  if (i >= (long)48 * 262144) return;
  int z = (int)(i >> 18);
  int rem = (int)(i & 262143);
  int k = rem >> 9, n = rem & 511;
  int layer = z >> 4, zz = z & 15, net = zz >> 3, m = zz & 7;
  const float* src = (net ? aW : cW) + (long)(layer * 8 + m) * 262144;
  float v = src[(long)k * 512 + n];
  int t = k >> 7, nb = n >> 4;
  int lane = ((k >> 5) & 3) * 16 + (n & 15);
  long off = ((((long)z * 4 + t) * 32 + nb) * 64 + lane) * 32 + (k & 31);
  dst[off] = f2fp8(16.f * v);
}

// merged biases lb[layer][z=net*8+m][n]
__global__ void k_pack_lb(const float* __restrict__ a_b, const float* __restrict__ c_b,
                          float* __restrict__ lb) {
  int i = blockIdx.x * 256 + threadIdx.x;         // 3*16*512 = 24576
  if (i >= 24576) return;
  int layer = i >> 13, zz = (i >> 9) & 15, n = i & 511;
  int net = zz >> 3, m = zz & 7;
  lb[i] = (net ? a_b : c_b)[(layer * 8 + m) * 512 + n];
}

// final-head weights -> fp8, x64 scaled, transposed [32 pad][4096]
__global__ void k_packwf8(const float* __restrict__ aWf, const float* __restrict__ cWf,
                          unsigned char* __restrict__ dsta, unsigned char* __restrict__ dstc) {
  int i = blockIdx.x * 256 + threadIdx.x;   // 131072 total
  int n = i >> 12, k = i & 4095;
  dsta[i] = (n < NACT) ? f2fp8(64.f * aWf[(long)k * NACT + n]) : (unsigned char)0;
  dstc[i] = (n < 1)    ? f2fp8(64.f * cWf[k])                  : (unsigned char)0;
}

__global__ void k_pack_rb(const float* __restrict__ a_rb, const float* __restrict__ c_rb,
                          float* __restrict__ rb) {
  int i = threadIdx.x;  // 384 threads
  rb[i] = (i < 192) ? a_rb[i] : c_rb[i - 192];
}

__global__ void k_sum_bf(const float* __restrict__ a_bf, const float* __restrict__ c_bf,
                         float* __restrict__ sa, float* __restrict__ sc) {
  int a = threadIdx.x;
  if (a < NACT) { float s = 0.f; for (int m = 0; m < 8; ++m) s += a_bf[m * NACT + a]; sa[a] = s; }
  if (a == 0)   { float s = 0.f; for (int m = 0; m < 8; ++m) s += c_bf[m];            sc[0] = s; }
}

// ---------------- unified MX fp8 GEMM (LDS path): encoder / routing ----------------
// OP: 1 = tanh -> fp8 (encoder-1); 5 = tanh->fp8 AND fp8(relu(tanh*temb)) (encoder-2)
//     4 = softmax over col-octets -> f32 (routing)
template <int OP>
__global__ __launch_bounds__(256, 4)
void k_gemm8(const unsigned char* __restrict__ A, const unsigned char* __restrict__ Bt,
             void* __restrict__ Cv, const float* __restrict__ bias,
             int N, int K, int lda, int ldc, int gx, int gy,
             const int* __restrict__ tidx, const float* __restrict__ temb,
             unsigned char* __restrict__ out2) {
  __shared__ alignas(16) unsigned char sA[128 * 128];
  __shared__ alignas(16) unsigned char sB[128 * 128];
  int bx, by, z;
  xcd_map(blockIdx.x, gx, gy, bx, by, z);
  const int tid  = threadIdx.x;
  const int wave = tid >> 6, lane = tid & 63;
  const int wr = (wave >> 1) * 64, wc = (wave & 1) * 64;
  const int row0 = by * 128, col0 = bx * 128;
  const int lcol = lane & 15, quad = lane >> 4;
  const int sw7 = lcol & 7;
  const int c0 = ((2 * quad)     ^ sw7) * 16;
  const int c1 = ((2 * quad + 1) ^ sw7) * 16;
  const int raA0 = (wr + lcol) * 128 + c0, raA1 = (wr + lcol) * 128 + c1;
  const int rbB0 = (wc + lcol) * 128 + c0, rbB1 = (wc + lcol) * 128 + c1;
  int aOff[4], bOff[4];
#pragma unroll
  for (int i = 0; i < 4; ++i) {
    int u = i * 256 + tid;
    int r = u >> 3, gc = (u & 7) ^ (r & 7);
    aOff[i] = (row0 + r) * lda + gc * 16;
    bOff[i] = (col0 + r) * K + gc * 16;
  }

  f32x4 acc[4][4] = {};

  for (int kt = 0; kt < K; kt += 128) {
#pragma unroll
    for (int i = 0; i < 4; ++i) gl16(A + aOff[i] + kt, &sA[i * 4096 + tid * 16]);
#pragma unroll
    for (int i = 0; i < 4; ++i) gl16(Bt + bOff[i] + kt, &sB[i * 4096 + tid * 16]);
    __syncthreads();
    i32x8 bv[4];
#pragma unroll
    for (int ni = 0; ni < 4; ++ni) {
      i32x4 blo = *(const i32x4*)&sB[rbB0 + ni * 2048];
      i32x4 bhi = *(const i32x4*)&sB[rbB1 + ni * 2048];
      bv[ni] = (i32x8){blo[0], blo[1], blo[2], blo[3], bhi[0], bhi[1], bhi[2], bhi[3]};
    }
#pragma unroll
    for (int mi = 0; mi < 4; ++mi) {
      i32x4 alo = *(const i32x4*)&sA[raA0 + mi * 2048];
      i32x4 ahi = *(const i32x4*)&sA[raA1 + mi * 2048];
      i32x8 af = (i32x8){alo[0], alo[1], alo[2], alo[3], ahi[0], ahi[1], ahi[2], ahi[3]};
#pragma unroll
      for (int ni = 0; ni < 4; ++ni)
        acc[mi][ni] = __builtin_amdgcn_mfma_scale_f32_16x16x128_f8f6f4(
            bv[ni], af, acc[mi][ni], 0, 0, 0, 0x7F, 0, 0x7F);
    }
    __syncthreads();
  }

#pragma unroll
  for (int ni = 0; ni < 4; ++ni) {
    int colb = col0 + wc + ni * 16 + quad * 4;
    if (colb >= N) continue;
    float4 bw = *(const float4*)&bias[colb];
#pragma unroll
    for (int mi = 0; mi < 4; ++mi) {
      int rowg = row0 + wr + mi * 16 + lcol;
      float v0 = acc[mi][ni][0] * 0.0625f + bw.x;
      float v1 = acc[mi][ni][1] * 0.0625f + bw.y;
      float v2 = acc[mi][ni][2] * 0.0625f + bw.z;
      float v3 = acc[mi][ni][3] * 0.0625f + bw.w;
      long idx = (long)rowg * ldc + colb;
      if (OP == 1) {
        float t0 = tanhf(v0), t1 = tanhf(v1), t2 = tanhf(v2), t3 = tanhf(v3);
        unsigned d = __builtin_amdgcn_cvt_pk_fp8_f32(t0, t1, 0, false);
        d = __builtin_amdgcn_cvt_pk_fp8_f32(t2, t3, d, true);
        *(unsigned*)&((unsigned char*)Cv)[idx] = d;
      } else if (OP == 5) {
        float t0 = tanhf(v0), t1 = tanhf(v1), t2 = tanhf(v2), t3 = tanhf(v3);
        unsigned d = __builtin_amdgcn_cvt_pk_fp8_f32(t0, t1, 0, false);
        d = __builtin_amdgcn_cvt_pk_fp8_f32(t2, t3, d, true);
        *(unsigned*)&((unsigned char*)Cv)[idx] = d;
        int tk = tidx[rowg];
        float4 te = *(const float4*)&temb[(long)tk * HD + colb];
        unsigned e = __builtin_amdgcn_cvt_pk_fp8_f32(fmaxf(t0 * te.x, 0.f), fmaxf(t1 * te.y, 0.f), 0, false);
        e = __builtin_amdgcn_cvt_pk_fp8_f32(fmaxf(t2 * te.z, 0.f), fmaxf(t3 * te.w, 0.f), e, true);
        *(unsigned*)&out2[idx] = e;
      } else if (OP == 4) {
        float mx = fmaxf(fmaxf(v0, v1), fmaxf(v2, v3));
        mx = fmaxf(mx, __shfl_xor(mx, 16));
        float e0 = __expf(v0 - mx), e1 = __expf(v1 - mx), e2 = __expf(v2 - mx), e3 = __expf(v3 - mx);
        float s = e0 + e1 + e2 + e3;
        s += __shfl_xor(s, 16);
        float inv = 1.f / s;
        *(float4*)&((float*)Cv)[idx] = make_float4(e0 * inv, e1 * inv, e2 * inv, e3 * inv);
      }
    }
  }
}

// ---------------- FUSED base-net layer v2: GEMM (8 modules) + routed combine ----------------
// Block = 64 rows x 64 h x one net; 8 waves; wave w = module w; acc[4][4] (<=128 VGPR).
// AMODE1: wave-PRIVATE A staging (own 8 KB LDS slice), NO barriers in K-loop,
// per-wave vmcnt(0) self-sync; AMODE0 (layer1): fs staged once block-wide, 1 barrier.
// W loaded direct from fragment-packed layout: base + lane*32 (coalesced dwordx4).
// sO (relu fp8, 32 KB) UNIONED over sA -> total LDS 64 KB (AMODE1) / 32 KB (AMODE0)
// -> 2 blocks/CU. Epilogue: in-LDS routed combine, only g hits HBM.
template <int AMODE>
__global__ __launch_bounds__(512, 4)
void k_gemmF(const unsigned char* __restrict__ A, const unsigned char* __restrict__ Wp,
             const float* __restrict__ lb, const float* __restrict__ probs,
             unsigned char* __restrict__ g, int gy, int poffC, int poffA) {
  __shared__ alignas(16) unsigned char sL[AMODE ? 65536 : 32768];
  int hb, slab, net;
  xcd_map(blockIdx.x, 8, gy, hb, slab, net);
  const int tid = threadIdx.x;
  const int w = tid >> 6, lane = tid & 63;
  const int lcol = lane & 15, quad = lane >> 4;
  const int ln3 = lane >> 3, sl = lane & 7;
  const int row0 = slab * 64;
  const int h0 = hb * 64;
  const int sw7 = lcol & 7;
  const int c0 = ((2 * quad)     ^ sw7) * 16;
  const int c1 = ((2 * quad + 1) ^ sw7) * 16;
  const int ch = sl ^ ln3;                       // staging chunk for this lane (const!)
  // fragment-packed W base for this wave: z=net*8+w, nb=hb*4+ni, +t*65536 +ni*2048
  const unsigned char* wbase =
      Wp + (((long)(net * 8 + w) * 4 * 32 + hb * 4) * 64 + lane) * 32;

  f32x4 acc[4][4] = {};

  if (AMODE == 0) {
    // stage fs slice [4 t][64 r][128 B] once; wave w issues v-blocks w*4..w*4+3
#pragma unroll
    for (int i = 0; i < 4; ++i) {
      int vb = w * 4 + i;
      int rr = (vb & 7) * 8 + ln3;
      gl16(A + (row0 + rr) * 512 + (vb >> 3) * 128 + ch * 16, &sL[(vb * 64 + lane) * 16]);
    }
    __syncthreads();   // implicit vmcnt drain; all waves share the staged fs
#pragma unroll
    for (int t = 0; t < 4; ++t) {
      i32x8 bv[4];
#pragma unroll
      for (int ni = 0; ni < 4; ++ni) {
        i32x4 lo = *(const i32x4*)(wbase + t * 65536 + ni * 2048);
        i32x4 hi = *(const i32x4*)(wbase + t * 65536 + ni * 2048 + 16);
        bv[ni] = (i32x8){lo[0], lo[1], lo[2], lo[3], hi[0], hi[1], hi[2], hi[3]};
      }
#pragma unroll
      for (int mi = 0; mi < 4; ++mi) {
        int ra = t * 8192 + (mi * 16 + lcol) * 128;
        i32x4 lo = *(const i32x4*)&sL[ra + c0];
        i32x4 hi = *(const i32x4*)&sL[ra + c1];
        i32x8 af = (i32x8){lo[0], lo[1], lo[2], lo[3], hi[0], hi[1], hi[2], hi[3]};
#pragma unroll
        for (int ni = 0; ni < 4; ++ni)
          acc[mi][ni] = __builtin_amdgcn_mfma_scale_f32_16x16x128_f8f6f4(
              bv[ni], af, acc[mi][ni], 0, 0, 0, 0x7F, 0, 0x7F);
      }
    }
  } else {
    // wave-private: A slice for module w, rows row0..row0+63. No block barriers.
    const unsigned char* abase = A + (long)(row0 + ln3) * 8192 + net * 4096 + w * 512 + ch * 16;
    unsigned char* dbase = &sL[w * 8192 + lane * 16];
#pragma unroll 1
    for (int t = 0; t < 4; ++t) {
      const int kt = t * 128;
#pragma unroll
      for (int i = 0; i < 8; ++i)
        gl16(abase + i * 8 * 8192 + kt, dbase + i * 1024);
      i32x8 bv[4];
#pragma unroll
      for (int ni = 0; ni < 4; ++ni) {
        i32x4 lo = *(const i32x4*)(wbase + t * 65536 + ni * 2048);
        i32x4 hi = *(const i32x4*)(wbase + t * 65536 + ni * 2048 + 16);
        bv[ni] = (i32x8){lo[0], lo[1], lo[2], lo[3], hi[0], hi[1], hi[2], hi[3]};
      }
      asm volatile("s_waitcnt vmcnt(0)" ::: "memory");   // own staging landed
      __builtin_amdgcn_sched_barrier(0);
#pragma unroll
      for (int mi = 0; mi < 4; ++mi) {
        int ra = w * 8192 + (mi * 16 + lcol) * 128;
        i32x4 lo = *(const i32x4*)&sL[ra + c0];
        i32x4 hi = *(const i32x4*)&sL[ra + c1];
        i32x8 af = (i32x8){lo[0], lo[1], lo[2], lo[3], hi[0], hi[1], hi[2], hi[3]};
#pragma unroll
        for (int ni = 0; ni < 4; ++ni)
          acc[mi][ni] = __builtin_amdgcn_mfma_scale_f32_16x16x128_f8f6f4(
              bv[ni], af, acc[mi][ni], 0, 0, 0, 0x7F, 0, 0x7F);
      }
    }
  }

  __syncthreads();   // all waves done with sL as A-staging; safe to overwrite with sO

  // ---- epilogue A: relu -> fp8 -> sO[j=w][64 r][16 dwords], dword-slot XOR (r&14) ----
#pragma unroll
  for (int ni = 0; ni < 4; ++ni) {
    int col = ni * 16 + quad * 4;                // 0..63
    float4 bw = *(const float4*)&lb[(net * 8 + w) * 512 + h0 + col];
    int sd = ni * 4 + quad;                      // dword slot 0..15
#pragma unroll
    for (int mi = 0; mi < 4; ++mi) {
      int row = mi * 16 + lcol;
      float v0 = fmaxf(acc[mi][ni][0] * 0.0625f + bw.x, 0.f);
      float v1 = fmaxf(acc[mi][ni][1] * 0.0625f + bw.y, 0.f);
      float v2 = fmaxf(acc[mi][ni][2] * 0.0625f + bw.z, 0.f);
      float v3 = fmaxf(acc[mi][ni][3] * 0.0625f + bw.w, 0.f);
      unsigned d = __builtin_amdgcn_cvt_pk_fp8_f32(v0, v1, 0, false);
      d = __builtin_amdgcn_cvt_pk_fp8_f32(v2, v3, d, true);
      *(unsigned*)&sL[w * 4096 + row * 64 + ((sd ^ (row & 14)) << 2)] = d;
    }
  }
  __syncthreads();

  // ---- epilogue B: routed combine from LDS; wave w = output module i = w ----
  const int poff = net ? poffA : poffC;
#pragma unroll
  for (int k = 0; k < 8; ++k) {
    const int r = k * 8 + ln3;
    const float* pr = &probs[(long)(row0 + r) * 384 + poff + w * 8];
    float4 pA = *(const float4*)pr;
    float4 pB = *(const float4*)(pr + 4);
    float p8[8] = {pA.x, pA.y, pA.z, pA.w, pB.x, pB.y, pB.z, pB.w};
    float ga[8] = {};
#pragma unroll
    for (int j = 0; j < 8; ++j) {
      uint2 o2 = *(const uint2*)&sL[j * 4096 + r * 64 + (((sl * 2) ^ (r & 14)) << 2)];
      float pw = p8[j];
      f32x2 a0 = __builtin_amdgcn_cvt_pk_f32_fp8(o2.x, false);
      f32x2 a1 = __builtin_amdgcn_cvt_pk_f32_fp8(o2.x, true);
      f32x2 a2 = __builtin_amdgcn_cvt_pk_f32_fp8(o2.y, false);
      f32x2 a3 = __builtin_amdgcn_cvt_pk_f32_fp8(o2.y, true);
      ga[0] += pw * a0.x; ga[1] += pw * a0.y; ga[2] += pw * a1.x; ga[3] += pw * a1.y;
      ga[4] += pw * a2.x; ga[5] += pw * a2.y; ga[6] += pw * a3.x; ga[7] += pw * a3.y;
    }
    unsigned lo = __builtin_amdgcn_cvt_pk_fp8_f32(ga[0], ga[1], 0, false);
    lo = __builtin_amdgcn_cvt_pk_fp8_f32(ga[2], ga[3], lo, true);
    unsigned hi = __builtin_amdgcn_cvt_pk_fp8_f32(ga[4], ga[5], 0, false);
    hi = __builtin_amdgcn_cvt_pk_fp8_f32(ga[6], ga[7], hi, true);
    *(uint2*)&g[(long)(row0 + r) * 8192 + net * 4096 + w * 512 + h0 + sl * 8] =
        make_uint2(lo, hi);
  }
}

// ---------------- MFMA head: out[:, ooff..) = g8[rows,4096(of lda)] * (64*Wf)^T / 64 + bsum ----
template <int NOUT>
__global__ __launch_bounds__(256)
void k_head8(const unsigned char* __restrict__ A, const unsigned char* __restrict__ Bt,
             const float* __restrict__ bsum, float* __restrict__ out, int lda, int ooff) {
  __shared__ alignas(16) unsigned char sA[64 * 64];
  __shared__ alignas(16) unsigned char sB[32 * 64];
  const int tid = threadIdx.x;
  const int wave = tid >> 6, lane = tid & 63;
  const int row0 = blockIdx.x * 64;
  const int lcol = lane & 15, quad = lane >> 4;
  const int sw = (lcol >> 1) & 3;
  const int co0 = (((quad >> 1)    ) ^ sw) * 16 + (quad & 1) * 8;
  const int co1 = (((quad >> 1) + 2) ^ sw) * 16 + (quad & 1) * 8;
  f32x4 acc[2] = {};

  for (int kt = 0; kt < 4096; kt += 64) {
    {
      int r = tid >> 2, gc = (tid & 3) ^ ((tid >> 3) & 3);
      gl16(A + (long)(row0 + r) * lda + kt + gc * 16, &sA[tid * 16]);
    }
    if (tid < 128) {
      int r = tid >> 2, gc = (tid & 3) ^ ((tid >> 3) & 3);
      gl16(Bt + (long)r * 4096 + kt + gc * 16, &sB[tid * 16]);
    }
    __syncthreads();
    long af[2], bv[2][2];
    int ra = (wave * 16 + lcol) * 64;
    af[0] = *(const long*)&sA[ra + co0];
    af[1] = *(const long*)&sA[ra + co1];
#pragma unroll
    for (int ni = 0; ni < 2; ++ni) {
      int rbq = (ni * 16 + lcol) * 64;
      bv[0][ni] = *(const long*)&sB[rbq + co0];
      bv[1][ni] = *(const long*)&sB[rbq + co1];
    }
#pragma unroll
    for (int kk = 0; kk < 2; ++kk)
#pragma unroll
      for (int ni = 0; ni < 2; ++ni)
        acc[ni] = __builtin_amdgcn_mfma_f32_16x16x32_fp8_fp8(af[kk], bv[kk][ni], acc[ni], 0, 0, 0);
    __syncthreads();
  }

#pragma unroll
  for (int ni = 0; ni < 2; ++ni) {
    int col = ni * 16 + lcol;
    if (col >= NOUT) continue;
#pragma unroll
    for (int r = 0; r < 4; ++r) {
      int row = row0 + wave * 16 + quad * 4 + r;
      out[(long)row * 20 + ooff + col] = acc[ni][r] * 0.015625f + bsum[col];
    }
  }
}

__global__ void k_logstd(const float* __restrict__ ls, float* __restrict__ out) {
  float lp = 0.f, ent = 0.f;
#pragma unroll
  for (int a = 0; a < NACT; ++a) {
    float v = ls[a];
    lp  += -v - LOG_SQRT_2PI;
    ent += 0.5f + LOG_SQRT_2PI + v;
  }
  long b = (long)blockIdx.x * 256 + threadIdx.x;
  if (b < BSZ) { out[b * 20 + 17] = lp; out[b * 20 + 18] = ent; }
}

// ---------------- host ----------------

extern "C" void kernel_launch(void* const* d_in, const int* in_sizes, int n_in,
                              void* d_out, int out_size, void* d_ws, size_t ws_size,
                              hipStream_t stream) {
  const float* x        = (const float*)d_in[0];
  const int*   task_idx = (const int*)d_in[1];
  const float* enc_W1   = (const float*)d_in[2];
  const float* enc_b1   = (const float*)d_in[3];
  const float* enc_W2   = (const float*)d_in[4];
  const float* enc_b2   = (const float*)d_in[5];
  const float* task_emb = (const float*)d_in[6];
  const float* a_rW     = (const float*)d_in[7];
  const float* a_rb     = (const float*)d_in[8];
  const float* c_rW     = (const float*)d_in[9];
  const float* c_rb     = (const float*)d_in[10];
  const float* a_W      = (const float*)d_in[11];
  const float* a_b      = (const float*)d_in[12];
  const float* a_Wf     = (const float*)d_in[13];
  const float* a_bf     = (const float*)d_in[14];
  const float* c_W      = (const float*)d_in[15];
  const float* c_b      = (const float*)d_in[16];
  const float* c_Wf     = (const float*)d_in[17];
  const float* c_bf     = (const float*)d_in[18];
  const float* logstd   = (const float*)d_in[19];
  float* out = (float*)d_out;

  char* ws = (char*)d_ws;
  size_t off = 0;
  auto carve = [&](size_t bytes) {
    char* p = ws + off;
    off += (bytes + 255) & ~(size_t)255;
    return p;
  };
  // ---- fixed region ----
  unsigned char* W8 = (unsigned char*)carve((size_t)48 * 262144);   // fragment-packed fp8 weights
  unsigned char* W1T8 = (unsigned char*)carve((size_t)512 * 512);   // enc W1^T fp8 x16, K-pad 512
  unsigned char* W2T8 = (unsigned char*)carve((size_t)512 * 512);   // enc W2^T fp8 x16
  unsigned char* rWT8 = (unsigned char*)carve((size_t)384 * 512);   // routing W^T fp8 x16
  float* rball = (float*)carve(384 * 4);
  float* lb    = (float*)carve(3 * 16 * 512 * 4);                   // merged biases
  unsigned char* WfaT8 = (unsigned char*)carve((size_t)32 * 4096);  // head weights fp8 x64, padded
  unsigned char* WfcT8 = (unsigned char*)carve((size_t)32 * 4096);
  float* bfa   = (float*)carve(128 * 4);
  float* bfc   = (float*)carve(128 * 4);
  unsigned char* fs8 = (unsigned char*)carve((size_t)BSZ * HD);
  float* lgt   = (float*)carve((size_t)BSZ * 384 * 4);

  // ---- fp8 ping-pong region ([Bc, 8192] each: critic cols 0..4096, actor 4096..8192) ----
  size_t remain = (ws_size > off) ? (ws_size - off) : 0;
  int Bc = 2048;
  for (int cand = BSZ; cand > 2048; cand >>= 1)
    if ((size_t)2 * cand * 8192 <= remain) { Bc = cand; break; }
  size_t half = (size_t)Bc * 8192;
  unsigned char* bufA8 = (unsigned char*)carve(half);
  unsigned char* bufB8 = (unsigned char*)carve(half);
  unsigned char* x8   = bufA8;   // [B,512] fp8, dead after enc1
  unsigned char* h18  = bufB8;   // [B,512] fp8, dead after enc2
  unsigned char* rel8 = bufA8;   // [B,512] fp8, dead after routing

  dim3 tb(32, 8);

  // ---- prep (all fp8 packs) ----
  k_cvt_pad8<<<(int)(((long)BSZ * HD + 255) / 256), 256, 0, stream>>>(x, x8);
  k_packT8<<<dim3(16, 16, 1), tb, 0, stream>>>(enc_W1, W1T8, OBSN, 512, 512, 0, 0, 16.f);
  k_packT8<<<dim3(16, 16, 1), tb, 0, stream>>>(enc_W2, W2T8, 512, 512, 512, 0, 0, 16.f);
  k_packT8<<<dim3(2, 16, 3),  tb, 0, stream>>>(a_rW, rWT8,             512, 64, 512, 512 * 64, 64 * 512, 16.f);
  k_packT8<<<dim3(2, 16, 3),  tb, 0, stream>>>(c_rW, rWT8 + 192 * 512, 512, 64, 512, 512 * 64, 64 * 512, 16.f);
  k_packwF<<<(int)(((long)48 * 262144 + 255) / 256), 256, 0, stream>>>(a_W, c_W, W8);
  k_pack_lb<<<96, 256, 0, stream>>>(a_b, c_b, lb);
  k_packwf8<<<512, 256, 0, stream>>>(a_Wf, c_Wf, WfaT8, WfcT8);
  k_pack_rb<<<1, 384, 0, stream>>>(a_rb, c_rb, rball);
  k_sum_bf<<<1, 32, 0, stream>>>(a_bf, c_bf, bfa, bfc);

  const int GY = BSZ / 128;
  // ---- encoder + routing (fp8 MX, LDS kernel) ----
  k_gemm8<1><<<4 * GY, 256, 0, stream>>>(x8, W1T8, h18, enc_b1, 512, 512, 512, 512,
                                         4, GY, nullptr, nullptr, nullptr);
  k_gemm8<5><<<4 * GY, 256, 0, stream>>>(h18, W2T8, fs8, enc_b2, 512, 512, 512, 512,
                                         4, GY, task_idx, task_emb, rel8);
  k_gemm8<4><<<3 * GY, 256, 0, stream>>>(rel8, rWT8, lgt, rball, 384, 512, 512, 384,
                                         3, GY, nullptr, nullptr, nullptr);

  // ---- base nets: fused GEMM+combine v2, 3 layers, chunked (Bc normally 16384) ----
  const size_t wlz = (size_t)16 * 262144;   // per-layer packed weight block
  for (int c0 = 0; c0 < BSZ; c0 += Bc) {
    const unsigned char* fs_c = fs8 + (long)c0 * 512;
    const float* pr_c  = lgt + (long)c0 * 384;
    float*       out_c = out + (long)c0 * 20;
    const int gyF = Bc / 64;

    k_gemmF<0><<<16 * gyF, 512, 0, stream>>>(fs_c, W8, lb, pr_c, bufA8, gyF, 192, 0);
    k_gemmF<1><<<16 * gyF, 512, 0, stream>>>(bufA8, W8 + wlz, lb + 8192, pr_c, bufB8,
                                             gyF, 192 + 64, 64);
    k_gemmF<1><<<16 * gyF, 512, 0, stream>>>(bufB8, W8 + 2 * wlz, lb + 16384, pr_c, bufA8,
                                             gyF, 192 + 128, 128);
    k_head8<1><<<Bc / 64, 256, 0, stream>>>(bufA8, WfcT8, bfc, out_c, 8192, 19);
    k_head8<NACT><<<Bc / 64, 256, 0, stream>>>(bufA8 + 4096, WfaT8, bfa, out_c, 8192, 0);
  }

  // ---- constants ----
  k_logstd<<<BSZ / 256, 256, 0, stream>>>(logstd, out);
}

// Round 8
// 739.504 us; speedup vs baseline: 1.5601x; 1.0244x over previous
//
#include <hip/hip_runtime.h>
#include <hip/hip_bf16.h>

typedef float f32x4 __attribute__((ext_vector_type(4)));
typedef float f32x2 __attribute__((ext_vector_type(2)));
typedef int   i32x4 __attribute__((ext_vector_type(4)));
typedef int   i32x8 __attribute__((ext_vector_type(8)));

#define LOG_SQRT_2PI 0.91893853320467274f

static constexpr int BSZ  = 16384;
static constexpr int OBSN = 376;
static constexpr int HD   = 512;
static constexpr int NACT = 17;

__device__ __forceinline__ unsigned char f2fp8(float v) {
  return (unsigned char)(__builtin_amdgcn_cvt_pk_fp8_f32(v, v, 0, false) & 0xFF);
}

__device__ __forceinline__ void gl16(const unsigned char* g, unsigned char* l) {
  __builtin_amdgcn_global_load_lds((const __attribute__((address_space(1))) void*)g,
                                   (__attribute__((address_space(3))) void*)l, 16, 0, 0);
}

// XCD-aware tile remap. Requires grid % 8 == 0.
__device__ __forceinline__ void xcd_map(int id, int gx, int gy, int& bx, int& by, int& bz) {
  int p = id & 7, l = id >> 3;
  bx = l % gx;
  int g = (l / gx) * 8 + p;
  by = g % gy;
  bz = g / gy;
}

// ---------------- prep kernels ----------------

// x [B,376] f32 -> [B,512] fp8 (zero pad)
__global__ void k_cvt_pad8(const float* __restrict__ src, unsigned char* __restrict__ dst) {
  long i = (long)blockIdx.x * 256 + threadIdx.x;
  if (i >= (long)BSZ * HD) return;
  long r = i >> 9;
  int  c = (int)(i & 511);
  dst[i] = f2fp8(c < OBSN ? src[r * OBSN + c] : 0.f);
}

// dst[n][k] = fp8(scale * src[k][n]); zero for k >= K. batched via blockIdx.z.
__global__ void k_packT8(const float* __restrict__ src, unsigned char* __restrict__ dst,
                         int K, int N, int Kpad, long sstride, long dstride, float scale) {
  __shared__ float t[32][33];
  src += (long)blockIdx.z * sstride;
  dst += (long)blockIdx.z * dstride;
  int k0 = blockIdx.y * 32, n0 = blockIdx.x * 32;
#pragma unroll
  for (int ii = 0; ii < 4; ++ii) {
    int i = ii * 8 + threadIdx.y;
    int k = k0 + i, n = n0 + threadIdx.x;
    t[i][threadIdx.x] = (k < K && n < N) ? src[(long)k * N + n] : 0.f;
  }
  __syncthreads();
#pragma unroll
  for (int ii = 0; ii < 4; ++ii) {
    int i = ii * 8 + threadIdx.y;
    int n = n0 + i, k = k0 + threadIdx.x;
    if (n < N && k < Kpad) dst[(long)n * Kpad + k] = f2fp8(scale * t[threadIdx.x][i]);
  }
}

// base-net weights -> FRAGMENT-PACKED fp8 x16 (per-wave coalesced dwordx4 loads).
__global__ void k_packwF(const float* __restrict__ aW, const float* __restrict__ cW,
                         unsigned char* __restrict__ dst) {
  long i = (long)blockIdx.x * 256 + threadIdx.x;   // 48*262144
  if (i >= (long)48 * 262144) return;
  int z = (int)(i >> 18);
  int rem = (int)(i & 262143);
  int k = rem >> 9, n = rem & 511;
  int layer = z >> 4, zz = z & 15, net = zz >> 3, m = zz & 7;
  const float* src = (net ? aW : cW) + (long)(layer * 8 + m) * 262144;
  float v = src[(long)k * 512 + n];
  int t = k >> 7, nb = n >> 4;
  int lane = ((k >> 5) & 3) * 16 + (n & 15);
  long off = ((((long)z * 4 + t) * 32 + nb) * 64 + lane) * 32 + (k & 31);
  dst[off] = f2fp8(16.f * v);
}

// merged biases lb[layer][z=net*8+m][n]
__global__ void k_pack_lb(const float* __restrict__ a_b, const float* __restrict__ c_b,
                          float* __restrict__ lb) {
  int i = blockIdx.x * 256 + threadIdx.x;         // 3*16*512 = 24576
  if (i >= 24576) return;
  int layer = i >> 13, zz = (i >> 9) & 15, n = i & 511;
  int net = zz >> 3, m = zz & 7;
  lb[i] = (net ? a_b : c_b)[(layer * 8 + m) * 512 + n];
}

// final-head weights -> fp8 x64, transposed [32 pad][4096], with the g-PERMUTED k axis:
// k_new = hb*512 + m*64 + u  <->  k_orig = m*512 + hb*64 + u.
__global__ void k_packwf8(const float* __restrict__ aWf, const float* __restrict__ cWf,
                          unsigned char* __restrict__ dsta, unsigned char* __restrict__ dstc) {
  int i = blockIdx.x * 256 + threadIdx.x;   // 131072 total
  int n = i >> 12, kn = i & 4095;
  int hb = kn >> 9, rem = kn & 511, m = rem >> 6, u = kn & 63;
  int ko = m * 512 + hb * 64 + u;
  dsta[i] = (n < NACT) ? f2fp8(64.f * aWf[(long)ko * NACT + n]) : (unsigned char)0;
  dstc[i] = (n < 1)    ? f2fp8(64.f * cWf[ko])                  : (unsigned char)0;
}

__global__ void k_pack_rb(const float* __restrict__ a_rb, const float* __restrict__ c_rb,
                          float* __restrict__ rb) {
  int i = threadIdx.x;  // 384 threads
  rb[i] = (i < 192) ? a_rb[i] : c_rb[i - 192];
}

__global__ void k_sum_bf(const float* __restrict__ a_bf, const float* __restrict__ c_bf,
                         float* __restrict__ sa, float* __restrict__ sc) {
  int a = threadIdx.x;
  if (a < NACT) { float s = 0.f; for (int m = 0; m < 8; ++m) s += a_bf[m * NACT + a]; sa[a] = s; }
  if (a == 0)   { float s = 0.f; for (int m = 0; m < 8; ++m) s += c_bf[m];            sc[0] = s; }
}

// out pre-init: actor cols 0..16 = bfa, col 19 = bfc, 17/18 = 0 (logstd overwrites later).
__global__ void k_initout(const float* __restrict__ bfa, const float* __restrict__ bfc,
                          float* __restrict__ out) {
  long i = (long)blockIdx.x * 256 + threadIdx.x;   // BSZ*20
  if (i >= (long)BSZ * 20) return;
  int o = (int)(i % 20);
  out[i] = (o < NACT) ? bfa[o] : (o == 19 ? bfc[0] : 0.f);
}

// ---------------- unified MX fp8 GEMM (LDS path): encoder / routing ----------------
// OP: 1 = tanh -> fp8 (encoder-1); 5 = tanh->fp8 AND fp8(relu(tanh*temb)) (encoder-2)
//     4 = softmax over col-octets -> f32 (routing)
template <int OP>
__global__ __launch_bounds__(256, 4)
void k_gemm8(const unsigned char* __restrict__ A, const unsigned char* __restrict__ Bt,
             void* __restrict__ Cv, const float* __restrict__ bias,
             int N, int K, int lda, int ldc, int gx, int gy,
             const int* __restrict__ tidx, const float* __restrict__ temb,
             unsigned char* __restrict__ out2) {
  __shared__ alignas(16) unsigned char sA[128 * 128];
  __shared__ alignas(16) unsigned char sB[128 * 128];
  int bx, by, z;
  xcd_map(blockIdx.x, gx, gy, bx, by, z);
  const int tid  = threadIdx.x;
  const int wave = tid >> 6, lane = tid & 63;
  const int wr = (wave >> 1) * 64, wc = (wave & 1) * 64;
  const int row0 = by * 128, col0 = bx * 128;
  const int lcol = lane & 15, quad = lane >> 4;
  const int sw7 = lcol & 7;
  const int c0 = ((2 * quad)     ^ sw7) * 16;
  const int c1 = ((2 * quad + 1) ^ sw7) * 16;
  const int raA0 = (wr + lcol) * 128 + c0, raA1 = (wr + lcol) * 128 + c1;
  const int rbB0 = (wc + lcol) * 128 + c0, rbB1 = (wc + lcol) * 128 + c1;
  int aOff[4], bOff[4];
#pragma unroll
  for (int i = 0; i < 4; ++i) {
    int u = i * 256 + tid;
    int r = u >> 3, gc = (u & 7) ^ (r & 7);
    aOff[i] = (row0 + r) * lda + gc * 16;
    bOff[i] = (col0 + r) * K + gc * 16;
  }

  f32x4 acc[4][4] = {};

  for (int kt = 0; kt < K; kt += 128) {
#pragma unroll
    for (int i = 0; i < 4; ++i) gl16(A + aOff[i] + kt, &sA[i * 4096 + tid * 16]);
#pragma unroll
    for (int i = 0; i < 4; ++i) gl16(Bt + bOff[i] + kt, &sB[i * 4096 + tid * 16]);
    __syncthreads();
    i32x8 bv[4];
#pragma unroll
    for (int ni = 0; ni < 4; ++ni) {
      i32x4 blo = *(const i32x4*)&sB[rbB0 + ni * 2048];
      i32x4 bhi = *(const i32x4*)&sB[rbB1 + ni * 2048];
      bv[ni] = (i32x8){blo[0], blo[1], blo[2], blo[3], bhi[0], bhi[1], bhi[2], bhi[3]};
    }
#pragma unroll
    for (int mi = 0; mi < 4; ++mi) {
      i32x4 alo = *(const i32x4*)&sA[raA0 + mi * 2048];
      i32x4 ahi = *(const i32x4*)&sA[raA1 + mi * 2048];
      i32x8 af = (i32x8){alo[0], alo[1], alo[2], alo[3], ahi[0], ahi[1], ahi[2], ahi[3]};
#pragma unroll
      for (int ni = 0; ni < 4; ++ni)
        acc[mi][ni] = __builtin_amdgcn_mfma_scale_f32_16x16x128_f8f6f4(
            bv[ni], af, acc[mi][ni], 0, 0, 0, 0x7F, 0, 0x7F);
    }
    __syncthreads();
  }

#pragma unroll
  for (int ni = 0; ni < 4; ++ni) {
    int colb = col0 + wc + ni * 16 + quad * 4;
    if (colb >= N) continue;
    float4 bw = *(const float4*)&bias[colb];
#pragma unroll
    for (int mi = 0; mi < 4; ++mi) {
      int rowg = row0 + wr + mi * 16 + lcol;
      float v0 = acc[mi][ni][0] * 0.0625f + bw.x;
      float v1 = acc[mi][ni][1] * 0.0625f + bw.y;
      float v2 = acc[mi][ni][2] * 0.0625f + bw.z;
      float v3 = acc[mi][ni][3] * 0.0625f + bw.w;
      long idx = (long)rowg * ldc + colb;
      if (OP == 1) {
        float t0 = tanhf(v0), t1 = tanhf(v1), t2 = tanhf(v2), t3 = tanhf(v3);
        unsigned d = __builtin_amdgcn_cvt_pk_fp8_f32(t0, t1, 0, false);
        d = __builtin_amdgcn_cvt_pk_fp8_f32(t2, t3, d, true);
        *(unsigned*)&((unsigned char*)Cv)[idx] = d;
      } else if (OP == 5) {
        float t0 = tanhf(v0), t1 = tanhf(v1), t2 = tanhf(v2), t3 = tanhf(v3);
        unsigned d = __builtin_amdgcn_cvt_pk_fp8_f32(t0, t1, 0, false);
        d = __builtin_amdgcn_cvt_pk_fp8_f32(t2, t3, d, true);
        *(unsigned*)&((unsigned char*)Cv)[idx] = d;
        int tk = tidx[rowg];
        float4 te = *(const float4*)&temb[(long)tk * HD + colb];
        unsigned e = __builtin_amdgcn_cvt_pk_fp8_f32(fmaxf(t0 * te.x, 0.f), fmaxf(t1 * te.y, 0.f), 0, false);
        e = __builtin_amdgcn_cvt_pk_fp8_f32(fmaxf(t2 * te.z, 0.f), fmaxf(t3 * te.w, 0.f), e, true);
        *(unsigned*)&out2[idx] = e;
      } else if (OP == 4) {
        float mx = fmaxf(fmaxf(v0, v1), fmaxf(v2, v3));
        mx = fmaxf(mx, __shfl_xor(mx, 16));
        float e0 = __expf(v0 - mx), e1 = __expf(v1 - mx), e2 = __expf(v2 - mx), e3 = __expf(v3 - mx);
        float s = e0 + e1 + e2 + e3;
        s += __shfl_xor(s, 16);
        float inv = 1.f / s;
        *(float4*)&((float*)Cv)[idx] = make_float4(e0 * inv, e1 * inv, e2 * inv, e3 * inv);
      }
    }
  }
}

// ---------------- FUSED base-net layer v3: GEMM (8 modules) + routed combine (+head) ----
// Block = 64 rows x 64 h x one net; 8 waves; wave w = module w; acc[4][4].
// g uses PERMUTED column layout: c' = hb*512 + w*64 + u  (u = h within 64-chunk)
// -> block's per-row g-write is one contiguous 512 B run (full 128 B lines).
// AMODE1 staging reads compensate via permuted global addresses (LDS layout unchanged).
// HEAD (layer 3): g never hits HBM; combine result kept in LDS (sG) as fp8, then the
// 18-output head MFMA runs per block over its contiguous 512-wide permuted K-slice and
// f32 partials are atomicAdd'ed into out (pre-initialized with bias sums).
template <int AMODE, int HEAD>
__global__ __launch_bounds__(512, 4)
void k_gemmF(const unsigned char* __restrict__ A, const unsigned char* __restrict__ Wp,
             const float* __restrict__ lb, const float* __restrict__ probs,
             unsigned char* __restrict__ g, int gy, int poffC, int poffA,
             const unsigned char* __restrict__ Wfc, const unsigned char* __restrict__ Wfa,
             float* __restrict__ outp) {
  __shared__ alignas(16) unsigned char sL[AMODE ? 65536 : 32768];
  int hb, slab, net;
  xcd_map(blockIdx.x, 8, gy, hb, slab, net);
  const int tid = threadIdx.x;
  const int w = tid >> 6, lane = tid & 63;
  const int lcol = lane & 15, quad = lane >> 4;
  const int ln3 = lane >> 3, sl = lane & 7;
  const int row0 = slab * 64;
  const int h0 = hb * 64;
  const int sw7 = lcol & 7;
  const int c0 = ((2 * quad)     ^ sw7) * 16;
  const int c1 = ((2 * quad + 1) ^ sw7) * 16;
  const int ch = sl ^ ln3;                       // staging chunk for this lane
  const unsigned char* wbase =
      Wp + (((long)(net * 8 + w) * 4 * 32 + hb * 4) * 64 + lane) * 32;

  f32x4 acc[4][4] = {};

  if (AMODE == 0) {
    // stage fs slice [4 t][64 r][128 B] once (fs is in ORIGINAL layout)
#pragma unroll
    for (int i = 0; i < 4; ++i) {
      int vb = w * 4 + i;
      int rr = (vb & 7) * 8 + ln3;
      gl16(A + (row0 + rr) * 512 + (vb >> 3) * 128 + ch * 16, &sL[(vb * 64 + lane) * 16]);
    }
    __syncthreads();
#pragma unroll
    for (int t = 0; t < 4; ++t) {
      i32x8 bv[4];
#pragma unroll
      for (int ni = 0; ni < 4; ++ni) {
        i32x4 lo = *(const i32x4*)(wbase + t * 65536 + ni * 2048);
        i32x4 hi = *(const i32x4*)(wbase + t * 65536 + ni * 2048 + 16);
        bv[ni] = (i32x8){lo[0], lo[1], lo[2], lo[3], hi[0], hi[1], hi[2], hi[3]};
      }
#pragma unroll
      for (int mi = 0; mi < 4; ++mi) {
        int ra = t * 8192 + (mi * 16 + lcol) * 128;
        i32x4 lo = *(const i32x4*)&sL[ra + c0];
        i32x4 hi = *(const i32x4*)&sL[ra + c1];
        i32x8 af = (i32x8){lo[0], lo[1], lo[2], lo[3], hi[0], hi[1], hi[2], hi[3]};
#pragma unroll
        for (int ni = 0; ni < 4; ++ni)
          acc[mi][ni] = __builtin_amdgcn_mfma_scale_f32_16x16x128_f8f6f4(
              bv[ni], af, acc[mi][ni], 0, 0, 0, 0x7F, 0, 0x7F);
      }
    }
  } else {
    // wave-private staging from PERMUTED g: module w's k-th byte lives at
    // net*4096 + (k>>6)*512 + w*64 + (k&63). 16B chunk ch: hb-part = ch>>2, u = (ch&3)*16.
    const unsigned char* abase = A + (long)(row0 + ln3) * 8192 + net * 4096 +
                                 w * 64 + (ch >> 2) * 512 + (ch & 3) * 16;
    unsigned char* dbase = &sL[w * 8192 + lane * 16];
#pragma unroll 1
    for (int t = 0; t < 4; ++t) {
#pragma unroll
      for (int i = 0; i < 8; ++i)
        gl16(abase + i * 8 * 8192 + t * 1024, dbase + i * 1024);
      i32x8 bv[4];
#pragma unroll
      for (int ni = 0; ni < 4; ++ni) {
        i32x4 lo = *(const i32x4*)(wbase + t * 65536 + ni * 2048);
        i32x4 hi = *(const i32x4*)(wbase + t * 65536 + ni * 2048 + 16);
        bv[ni] = (i32x8){lo[0], lo[1], lo[2], lo[3], hi[0], hi[1], hi[2], hi[3]};
      }
      asm volatile("s_waitcnt vmcnt(0)" ::: "memory");
      __builtin_amdgcn_sched_barrier(0);
#pragma unroll
      for (int mi = 0; mi < 4; ++mi) {
        int ra = w * 8192 + (mi * 16 + lcol) * 128;
        i32x4 lo = *(const i32x4*)&sL[ra + c0];
        i32x4 hi = *(const i32x4*)&sL[ra + c1];
        i32x8 af = (i32x8){lo[0], lo[1], lo[2], lo[3], hi[0], hi[1], hi[2], hi[3]};
#pragma unroll
        for (int ni = 0; ni < 4; ++ni)
          acc[mi][ni] = __builtin_amdgcn_mfma_scale_f32_16x16x128_f8f6f4(
              bv[ni], af, acc[mi][ni], 0, 0, 0, 0x7F, 0, 0x7F);
      }
    }
  }

  __syncthreads();   // sL staging dead; reuse as sO (and sG for HEAD)

  // ---- epilogue A: relu -> fp8 -> sO[j=w][64 r][16 dwords], dword-slot XOR (r&14) ----
#pragma unroll
  for (int ni = 0; ni < 4; ++ni) {
    int col = ni * 16 + quad * 4;                // 0..63
    float4 bw = *(const float4*)&lb[(net * 8 + w) * 512 + h0 + col];
    int sd = ni * 4 + quad;                      // dword slot 0..15
#pragma unroll
    for (int mi = 0; mi < 4; ++mi) {
      int row = mi * 16 + lcol;
      float v0 = fmaxf(acc[mi][ni][0] * 0.0625f + bw.x, 0.f);
      float v1 = fmaxf(acc[mi][ni][1] * 0.0625f + bw.y, 0.f);
      float v2 = fmaxf(acc[mi][ni][2] * 0.0625f + bw.z, 0.f);
      float v3 = fmaxf(acc[mi][ni][3] * 0.0625f + bw.w, 0.f);
      unsigned d = __builtin_amdgcn_cvt_pk_fp8_f32(v0, v1, 0, false);
      d = __builtin_amdgcn_cvt_pk_fp8_f32(v2, v3, d, true);
      *(unsigned*)&sL[w * 4096 + row * 64 + ((sd ^ (row & 14)) << 2)] = d;
    }
  }
  __syncthreads();

  // ---- epilogue B: routed combine from LDS; wave w = output module i = w ----
  const int poff = net ? poffA : poffC;
#pragma unroll
  for (int k = 0; k < 8; ++k) {
    const int r = k * 8 + ln3;
    const float* pr = &probs[(long)(row0 + r) * 384 + poff + w * 8];
    float4 pA = *(const float4*)pr;
    float4 pB = *(const float4*)(pr + 4);
    float p8[8] = {pA.x, pA.y, pA.z, pA.w, pB.x, pB.y, pB.z, pB.w};
    float ga[8] = {};
#pragma unroll
    for (int j = 0; j < 8; ++j) {
      uint2 o2 = *(const uint2*)&sL[j * 4096 + r * 64 + (((sl * 2) ^ (r & 14)) << 2)];
      float pw = p8[j];
      f32x2 a0 = __builtin_amdgcn_cvt_pk_f32_fp8(o2.x, false);
      f32x2 a1 = __builtin_amdgcn_cvt_pk_f32_fp8(o2.x, true);
      f32x2 a2 = __builtin_amdgcn_cvt_pk_f32_fp8(o2.y, false);
      f32x2 a3 = __builtin_amdgcn_cvt_pk_f32_fp8(o2.y, true);
      ga[0] += pw * a0.x; ga[1] += pw * a0.y; ga[2] += pw * a1.x; ga[3] += pw * a1.y;
      ga[4] += pw * a2.x; ga[5] += pw * a2.y; ga[6] += pw * a3.x; ga[7] += pw * a3.y;
    }
    unsigned lo = __builtin_amdgcn_cvt_pk_fp8_f32(ga[0], ga[1], 0, false);
    lo = __builtin_amdgcn_cvt_pk_fp8_f32(ga[2], ga[3], lo, true);
    unsigned hi = __builtin_amdgcn_cvt_pk_fp8_f32(ga[4], ga[5], 0, false);
    hi = __builtin_amdgcn_cvt_pk_fp8_f32(ga[6], ga[7], hi, true);
    if (HEAD) {
      // keep g in LDS (sG at +32768), same [i][r][dword-XOR] layout as sO
      *(uint2*)&sL[32768 + w * 4096 + r * 64 + (((sl * 2) ^ (r & 14)) << 2)] =
          make_uint2(lo, hi);
    } else {
      // PERMUTED global g: row base + net*4096 + hb*512 + w*64 + sl*8 (full-line tiling)
      *(uint2*)&g[(long)(row0 + r) * 8192 + net * 4096 + hb * 512 + w * 64 + sl * 8] =
          make_uint2(lo, hi);
    }
  }

  if (HEAD) {
    __syncthreads();
    // head over this block's contiguous permuted K-slice [hb*512, hb*512+512).
    // wave w: m-tile mi = w&3 (rows mi*16..+16), K-half kh = w>>2 (256 wide).
    const unsigned char* Wf = net ? Wfa : Wfc;
    const int ooff = net ? 0 : 19;
    const int mi = w & 3, kh = w >> 2;
    const int hrow = mi * 16 + lcol;
    f32x4 hacc[2] = {};
#pragma unroll
    for (int ks = 0; ks < 8; ++ks) {
      int j = kh * 4 + (ks >> 1);                    // module slot in sG
      int u = (ks & 1) * 32 + quad * 8;              // byte within 64-chunk
      int sd = u >> 2;
      long af = *(const long*)&sL[32768 + j * 4096 + hrow * 64 + ((sd ^ (hrow & 14)) << 2)];
      int kglob = hb * 512 + kh * 256 + ks * 32 + quad * 8;
      long bv0 = *(const long*)&Wf[(long)lcol * 4096 + kglob];
      hacc[0] = __builtin_amdgcn_mfma_f32_16x16x32_fp8_fp8(af, bv0, hacc[0], 0, 0, 0);
      if (net) {
        long bv1 = *(const long*)&Wf[(long)(16 + lcol) * 4096 + kglob];
        hacc[1] = __builtin_amdgcn_mfma_f32_16x16x32_fp8_fp8(af, bv1, hacc[1], 0, 0, 0);
      }
    }
    const int NOUTn = net ? NACT : 1;
#pragma unroll
    for (int ni = 0; ni < 2; ++ni) {
      if (ni == 1 && !net) break;
      int col = ni * 16 + lcol;
      if (col >= NOUTn) continue;
#pragma unroll
      for (int rr = 0; rr < 4; ++rr) {
        int row = row0 + mi * 16 + quad * 4 + rr;
        atomicAdd(&outp[(long)row * 20 + ooff + col], hacc[ni][rr] * 0.015625f);
      }
    }
  }
}

__global__ void k_logstd(const float* __restrict__ ls, float* __restrict__ out) {
  float lp = 0.f, ent = 0.f;
#pragma unroll
  for (int a = 0; a < NACT; ++a) {
    float v = ls[a];
    lp  += -v - LOG_SQRT_2PI;
    ent += 0.5f + LOG_SQRT_2PI + v;
  }
  long b = (long)blockIdx.x * 256 + threadIdx.x;
  if (b < BSZ) { out[b * 20 + 17] = lp; out[b * 20 + 18] = ent; }
}

// ---------------- host ----------------

extern "C" void kernel_launch(void* const* d_in, const int* in_sizes, int n_in,
                              void* d_out, int out_size, void* d_ws, size_t ws_size,
                              hipStream_t stream) {
  const float* x        = (const float*)d_in[0];
  const int*   task_idx = (const int*)d_in[1];
  const float* enc_W1   = (const float*)d_in[2];
  const float* enc_b1   = (const float*)d_in[3];
  const float* enc_W2   = (const float*)d_in[4];
  const float* enc_b2   = (const float*)d_in[5];
  const float* task_emb = (const float*)d_in[6];
  const float* a_rW     = (const float*)d_in[7];
  const float* a_rb     = (const float*)d_in[8];
  const float* c_rW     = (const float*)d_in[9];
  const float* c_rb     = (const float*)d_in[10];
  const float* a_W      = (const float*)d_in[11];
  const float* a_b      = (const float*)d_in[12];
  const float* a_Wf     = (const float*)d_in[13];
  const float* a_bf     = (const float*)d_in[14];
  const float* c_W      = (const float*)d_in[15];
  const float* c_b      = (const float*)d_in[16];
  const float* c_Wf     = (const float*)d_in[17];
  const float* c_bf     = (const float*)d_in[18];
  const float* logstd   = (const float*)d_in[19];
  float* out = (float*)d_out;

  char* ws = (char*)d_ws;
  size_t off = 0;
  auto carve = [&](size_t bytes) {
    char* p = ws + off;
    off += (bytes + 255) & ~(size_t)255;
    return p;
  };
  // ---- fixed region ----
  unsigned char* W8 = (unsigned char*)carve((size_t)48 * 262144);   // fragment-packed fp8 weights
  unsigned char* W1T8 = (unsigned char*)carve((size_t)512 * 512);   // enc W1^T fp8 x16, K-pad 512
  unsigned char* W2T8 = (unsigned char*)carve((size_t)512 * 512);   // enc W2^T fp8 x16
  unsigned char* rWT8 = (unsigned char*)carve((size_t)384 * 512);   // routing W^T fp8 x16
  float* rball = (float*)carve(384 * 4);
  float* lb    = (float*)carve(3 * 16 * 512 * 4);                   // merged biases
  unsigned char* WfaT8 = (unsigned char*)carve((size_t)32 * 4096);  // head weights fp8 x64, perm-k
  unsigned char* WfcT8 = (unsigned char*)carve((size_t)32 * 4096);
  float* bfa   = (float*)carve(128 * 4);
  float* bfc   = (float*)carve(128 * 4);
  unsigned char* fs8 = (unsigned char*)carve((size_t)BSZ * HD);
  float* lgt   = (float*)carve((size_t)BSZ * 384 * 4);

  // ---- fp8 ping-pong region ([Bc, 8192] each) ----
  size_t remain = (ws_size > off) ? (ws_size - off) : 0;
  int Bc = 2048;
  for (int cand = BSZ; cand > 2048; cand >>= 1)
    if ((size_t)2 * cand * 8192 <= remain) { Bc = cand; break; }
  size_t half = (size_t)Bc * 8192;
  unsigned char* bufA8 = (unsigned char*)carve(half);
  unsigned char* bufB8 = (unsigned char*)carve(half);
  unsigned char* x8   = bufA8;   // [B,512] fp8, dead after enc1
  unsigned char* h18  = bufB8;   // [B,512] fp8, dead after enc2
  unsigned char* rel8 = bufA8;   // [B,512] fp8, dead after routing

  dim3 tb(32, 8);

  // ---- prep (all fp8 packs) ----
  k_cvt_pad8<<<(int)(((long)BSZ * HD + 255) / 256), 256, 0, stream>>>(x, x8);
  k_packT8<<<dim3(16, 16, 1), tb, 0, stream>>>(enc_W1, W1T8, OBSN, 512, 512, 0, 0, 16.f);
  k_packT8<<<dim3(16, 16, 1), tb, 0, stream>>>(enc_W2, W2T8, 512, 512, 512, 0, 0, 16.f);
  k_packT8<<<dim3(2, 16, 3),  tb, 0, stream>>>(a_rW, rWT8,             512, 64, 512, 512 * 64, 64 * 512, 16.f);
  k_packT8<<<dim3(2, 16, 3),  tb, 0, stream>>>(c_rW, rWT8 + 192 * 512, 512, 64, 512, 512 * 64, 64 * 512, 16.f);
  k_packwF<<<(int)(((long)48 * 262144 + 255) / 256), 256, 0, stream>>>(a_W, c_W, W8);
  k_pack_lb<<<96, 256, 0, stream>>>(a_b, c_b, lb);
  k_packwf8<<<512, 256, 0, stream>>>(a_Wf, c_Wf, WfaT8, WfcT8);
  k_pack_rb<<<1, 384, 0, stream>>>(a_rb, c_rb, rball);
  k_sum_bf<<<1, 32, 0, stream>>>(a_bf, c_bf, bfa, bfc);
  k_initout<<<(int)(((long)BSZ * 20 + 255) / 256), 256, 0, stream>>>(bfa, bfc, out);

  const int GY = BSZ / 128;
  // ---- encoder + routing (fp8 MX, LDS kernel) ----
  k_gemm8<1><<<4 * GY, 256, 0, stream>>>(x8, W1T8, h18, enc_b1, 512, 512, 512, 512,
                                         4, GY, nullptr, nullptr, nullptr);
  k_gemm8<5><<<4 * GY, 256, 0, stream>>>(h18, W2T8, fs8, enc_b2, 512, 512, 512, 512,
                                         4, GY, task_idx, task_emb, rel8);
  k_gemm8<4><<<3 * GY, 256, 0, stream>>>(rel8, rWT8, lgt, rball, 384, 512, 512, 384,
                                         3, GY, nullptr, nullptr, nullptr);

  // ---- base nets: fused GEMM+combine v3, layer 3 fuses heads ----
  const size_t wlz = (size_t)16 * 262144;   // per-layer packed weight block
  for (int c0 = 0; c0 < BSZ; c0 += Bc) {
    const unsigned char* fs_c = fs8 + (long)c0 * 512;
    const float* pr_c  = lgt + (long)c0 * 384;
    float*       out_c = out + (long)c0 * 20;
    const int gyF = Bc / 64;

    k_gemmF<0, 0><<<16 * gyF, 512, 0, stream>>>(fs_c, W8, lb, pr_c, bufA8, gyF, 192, 0,
                                                nullptr, nullptr, nullptr);
    k_gemmF<1, 0><<<16 * gyF, 512, 0, stream>>>(bufA8, W8 + wlz, lb + 8192, pr_c, bufB8,
                                                gyF, 192 + 64, 64, nullptr, nullptr, nullptr);
    k_gemmF<1, 1><<<16 * gyF, 512, 0, stream>>>(bufB8, W8 + 2 * wlz, lb + 16384, pr_c, bufA8,
                                                gyF, 192 + 128, 128, WfcT8, WfaT8, out_c);
  }

  // ---- constants ----
  k_logstd<<<BSZ / 256, 256, 0, stream>>>(logstd, out);
}